// Round 6
// baseline (889.043 us; speedup 1.0000x reference)
//
#include <hip/hip_runtime.h>
#include <hip/hip_bf16.h>

// Problem constants (from reference)
constexpr int Nn = 20000;   // nodes
constexpr int D  = 256;     // feature dim
constexpr int S  = 4;       // snapshots
constexpr int E  = 320000;  // edges
constexpr int H  = 5;       // horizon
constexpr int L  = 3;       // GCN layers

using bf16 = __hip_bfloat16;
typedef __attribute__((ext_vector_type(8))) short v8s;   // 8 bf16 = 4 VGPRs
typedef __attribute__((ext_vector_type(4))) float v4f;   // MFMA acc

#define GLOBAL_AS __attribute__((address_space(1)))
#define LDS_AS    __attribute__((address_space(3)))

__device__ __forceinline__ float gelu_exact(float x) {
    return 0.5f * x * (1.0f + erff(x * 0.70710678118654752440f));
}
__device__ __forceinline__ unsigned short f2bu(float f) {
    bf16 h = __float2bfloat16(f);
    return *reinterpret_cast<unsigned short*>(&h);
}
__device__ __forceinline__ float b2f(unsigned short u) {
    unsigned int v = (unsigned int)u << 16;
    return __uint_as_float(v);
}

// ---------------- fused preprocessing kernels ----------------
__global__ void init_deg_cnt_kernel(float* deg, int* cnt, int n) {
    int i = blockIdx.x * blockDim.x + threadIdx.x;
    if (i < n) { deg[i] = 1.0f; cnt[i] = 0; }
}
__global__ void deg_hist_kernel(const int* __restrict__ dst, const float* __restrict__ w,
                                float* __restrict__ deg, int* __restrict__ cnt, int e) {
    int i = blockIdx.x * blockDim.x + threadIdx.x;
    if (i < e) {
        int d = dst[i];
        atomicAdd(&deg[d], w[i]);
        atomicAdd(&cnt[d], 1);
    }
}
__global__ void dinv_kernel(const float* __restrict__ deg, float* __restrict__ dinv,
                            float* __restrict__ selfnorm, int n) {
    int i = blockIdx.x * blockDim.x + threadIdx.x;
    if (i < n) {
        float dg = deg[i];
        float dv = dg > 0.0f ? rsqrtf(fmaxf(dg, 1e-5f)) : 0.0f;
        dinv[i] = dv;
        selfnorm[i] = dv * dv;
    }
}
// 1024-thread exclusive scan over cnt[0..n) -> rowptr[0..n]; zeroes cnt.
__global__ __launch_bounds__(1024) void scan_rowptr_kernel(int* __restrict__ cnt,
                                                           int* __restrict__ rowptr, int n) {
    __shared__ int wsum[16];
    __shared__ int woff[16];
    int t = threadIdx.x;
    int wave = t >> 6, lane = t & 63;
    int chunk = (n + 1023) / 1024;
    int start = t * chunk;
    int end = start + chunk; if (end > n) end = n;
    int s = 0;
    for (int i = start; i < end; ++i) s += cnt[i];
    int incl = s;
#pragma unroll
    for (int off = 1; off < 64; off <<= 1) {
        int v = __shfl_up(incl, off);
        if (lane >= off) incl += v;
    }
    int excl = incl - s;
    if (lane == 63) wsum[wave] = incl;
    __syncthreads();
    if (t == 0) {
        int acc = 0;
        for (int i = 0; i < 16; ++i) { woff[i] = acc; acc += wsum[i]; }
        rowptr[n] = acc;
    }
    __syncthreads();
    int acc = woff[wave] + excl;
    for (int i = start; i < end; ++i) {
        rowptr[i] = acc; acc += cnt[i]; cnt[i] = 0;
    }
}
// fill CSR with packed (src, norm) per edge
__global__ void csr_fill_kernel(const int* __restrict__ src, const int* __restrict__ dst,
                                const float* __restrict__ w, const float* __restrict__ dinv,
                                const int* __restrict__ rowptr,
                                int* __restrict__ cursor, int2* __restrict__ esw, int e) {
    int i = blockIdx.x * blockDim.x + threadIdx.x;
    if (i < e) {
        int sN = src[i], dN = dst[i];
        int pos = rowptr[dN] + atomicAdd(&cursor[dN], 1);
        float nrm = dinv[sN] * w[i] * dinv[dN];
        esw[pos] = make_int2(sN, __float_as_int(nrm));
    }
}
// All weight conversions + GRU bias combine in one kernel.
constexpr int CW0 = L * D * D;          // gcn_W -> Wtb (transposed)
constexpr int CW1 = CW0 + 3 * D * D;    // Wih
constexpr int CW2 = CW1 + 3 * D * D;    // Whh
constexpr int CW3 = CW2 + 128 * 256;    // fc1W
constexpr int CW4 = CW3 + 64 * 128;     // fc2W
constexpr int CW5 = CW4 + 64 * 256;     // dh1W
constexpr int CW6 = CW5 + 4 * D;        // br, bz, big, bhg
__global__ void convert_weights_kernel(
    const float* __restrict__ gcn_W, const float* __restrict__ Wih,
    const float* __restrict__ Whh, const float* __restrict__ fc1W,
    const float* __restrict__ fc2W, const float* __restrict__ dh1W,
    const float* __restrict__ bih, const float* __restrict__ bhh,
    unsigned short* __restrict__ Wtb, unsigned short* __restrict__ Wihb,
    unsigned short* __restrict__ Whhb, unsigned short* __restrict__ fc1Wb,
    unsigned short* __restrict__ fc2Wb, unsigned short* __restrict__ dh1Wb,
    float* __restrict__ gbias)   // [4*D]: br, bz, big, bhg
{
    int i = blockIdx.x * blockDim.x + threadIdx.x;
    if (i < CW0) {
        int l = i / (D * D);
        int rem = i - l * D * D;
        int k = rem / D;
        int n = rem - k * D;
        Wtb[(size_t)l * D * D + (size_t)n * D + k] = f2bu(gcn_W[i]);
    } else if (i < CW1) { int j = i - CW0; Wihb[j]  = f2bu(Wih[j]);  }
    else if (i < CW2)   { int j = i - CW1; Whhb[j]  = f2bu(Whh[j]);  }
    else if (i < CW3)   { int j = i - CW2; fc1Wb[j] = f2bu(fc1W[j]); }
    else if (i < CW4)   { int j = i - CW3; fc2Wb[j] = f2bu(fc2W[j]); }
    else if (i < CW5)   { int j = i - CW4; dh1Wb[j] = f2bu(dh1W[j]); }
    else if (i < CW6) {
        int j = i - CW5;           // 0..1023
        int g = j >> 8, d = j & 255;
        float v;
        if (g == 0)      v = bih[d] + bhh[d];            // br
        else if (g == 1) v = bih[D + d] + bhh[D + d];    // bz
        else if (g == 2) v = bih[2 * D + d];             // big
        else             v = bhh[2 * D + d];             // bhg
        gbias[j] = v;
    }
}
__global__ void init_h_kernel(float* h, unsigned short* hb, int n) {
    int i = blockIdx.x * blockDim.x + threadIdx.x;
    if (i < n) { h[i] = 0.0f; hb[i] = 0; }
}
// x [S,N,D] f32 -> blocked [n*S+s][D] bf16, vectorized x4
__global__ __launch_bounds__(256) void x_to_blocked_kernel(const float* __restrict__ x,
                                                           unsigned short* __restrict__ out) {
    int tid = blockIdx.x * blockDim.x + threadIdx.x;   // over Nn*S*D/4
    if (tid >= Nn * S * (D / 4)) return;
    int row = tid >> 6;           // / 64 : row = s*Nn + n
    int r64 = tid & 63;
    int s = row / Nn;
    int n = row - s * Nn;
    float4 v = ((const float4*)x)[(size_t)row * 64 + r64];
    ushort4 u;
    u.x = f2bu(v.x); u.y = f2bu(v.y); u.z = f2bu(v.z); u.w = f2bu(v.w);
    ((ushort4*)out)[((size_t)(n * 4 + s)) * 64 + r64] = u;
}

// ---------------- bf16 MFMA GEMM: C = A[M,K](lda) * B[N,K]^T (+bias) -------------
// OUT_MODE 1: bf16 C[M,N] row-major (store-guarded on M and N; gelu if ACT).
// OUT_MODE 2: bf16 gather layout [node][dim][snap]: row gm = node*4+snap (M%128==0).
#define GBM 128
#define GBN 128
#define GBK 64
template<int OUT_MODE, int ACT>
__global__ __launch_bounds__(256) void gemm_bt_bf16_kernel(
    const unsigned short* __restrict__ A, int lda,
    const unsigned short* __restrict__ B,
    const float* __restrict__ bias, unsigned short* __restrict__ C,
    int M, int N, int K)
{
    __shared__ short As[GBM * GBK];
    __shared__ short Bs[GBN * GBK];
    int tid = threadIdx.x;
    int wave = tid >> 6, lane = tid & 63;
    int ln = lane & 15, quad = lane >> 4;
    int wr = wave >> 1, wc = wave & 1;
    int bm = blockIdx.y * GBM, bn = blockIdx.x * GBN;

    v4f acc[4][4];
#pragma unroll
    for (int i = 0; i < 4; ++i)
#pragma unroll
        for (int j = 0; j < 4; ++j)
            acc[i][j] = (v4f)(0.0f);

    int lrow = lane >> 3;          // 0..7 within 8-row segment
    int lcol = (lane & 7) * 8;     // bf16 col offset, 16B chunks

    for (int k0 = 0; k0 < K; k0 += GBK) {
#pragma unroll
        for (int c = 0; c < 4; ++c) {
            int seg = wave * 4 + c;           // 0..15
            int row = seg * 8 + lrow;         // 0..127
            int gm = bm + row; if (gm >= M) gm = M - 1;   // clamp: dup rows, never stored
            __builtin_amdgcn_global_load_lds(
                (const GLOBAL_AS unsigned int*)(A + (size_t)gm * lda + k0 + lcol),
                (LDS_AS unsigned int*)(&As[row * GBK + lcol]), 16, 0, 0);
            int gn = bn + row; if (gn >= N) gn = N - 1;   // clamp for N=64/128 heads
            __builtin_amdgcn_global_load_lds(
                (const GLOBAL_AS unsigned int*)(B + (size_t)gn * K + k0 + lcol),
                (LDS_AS unsigned int*)(&Bs[row * GBK + lcol]), 16, 0, 0);
        }
        __syncthreads();
#pragma unroll
        for (int ks = 0; ks < 2; ++ks) {
            v8s af[4], bfr[4];
#pragma unroll
            for (int i = 0; i < 4; ++i) {
                int row = wr * 64 + i * 16 + ln;
                af[i] = *(const v8s*)(&As[row * GBK + ks * 32 + quad * 8]);
            }
#pragma unroll
            for (int j = 0; j < 4; ++j) {
                int row = wc * 64 + j * 16 + ln;
                bfr[j] = *(const v8s*)(&Bs[row * GBK + ks * 32 + quad * 8]);
            }
#pragma unroll
            for (int i = 0; i < 4; ++i)
#pragma unroll
                for (int j = 0; j < 4; ++j)
                    acc[i][j] = __builtin_amdgcn_mfma_f32_16x16x32_bf16(af[i], bfr[j], acc[i][j], 0, 0, 0);
        }
        __syncthreads();
    }
    // epilogue: C/D layout col=lane&15, row=quad*4+reg
#pragma unroll
    for (int i = 0; i < 4; ++i) {
        int gmb = bm + wr * 64 + i * 16 + quad * 4;   // base row, multiple of 4
#pragma unroll
        for (int j = 0; j < 4; ++j) {
            int gn = bn + wc * 64 + j * 16 + ln;
            float bv = (bias && gn < N) ? bias[gn] : 0.0f;
            if (OUT_MODE == 2) {
                ushort4 u;
                u.x = f2bu(acc[i][j][0] + bv);
                u.y = f2bu(acc[i][j][1] + bv);
                u.z = f2bu(acc[i][j][2] + bv);
                u.w = f2bu(acc[i][j][3] + bv);
                int node = gmb >> 2;
                *(ushort4*)(C + ((size_t)node * D + gn) * 4) = u;
            } else {
                if (gn < N) {
#pragma unroll
                    for (int r = 0; r < 4; ++r) {
                        int gm = gmb + r;
                        if (gm < M) {
                            float v = acc[i][j][r] + bv;
                            if (ACT == 1) v = gelu_exact(v);
                            C[(size_t)gm * N + gn] = f2bu(v);
                        }
                    }
                }
            }
        }
    }
}

// ---------------- fused GRU step: both GEMMs + gates in one kernel ----------------
__global__ __launch_bounds__(256) void gru_fused_kernel(
    const unsigned short* __restrict__ feat, int fstride,   // phase-0 A
    const unsigned short* __restrict__ hbf,                 // phase-1 A  [node][D]
    const unsigned short* __restrict__ Wihb,                // [3*D][D]
    const unsigned short* __restrict__ Whhb,
    const float* __restrict__ gbias,                        // [4*D] br,bz,big,bhg
    float* __restrict__ h, unsigned short* __restrict__ hb, int write_f32)
{
    __shared__ short As[64 * 64];     // 8 KB
    __shared__ short Bs[192 * 64];    // 24 KB (3 gates x 64 dims)
    int tid = threadIdx.x;
    int wave = tid >> 6, lane = tid & 63;
    int ln = lane & 15, quad = lane >> 4;
    int wm = wave >> 1, wn = wave & 1;
    int bm = blockIdx.y * 64;
    int bn = blockIdx.x * 64;        // dim block

    v4f accR[2][2], accZ[2][2], accG[2][2], accHG[2][2];
#pragma unroll
    for (int mi = 0; mi < 2; ++mi)
#pragma unroll
        for (int nj = 0; nj < 2; ++nj) {
            accR[mi][nj] = (v4f)(0.0f); accZ[mi][nj] = (v4f)(0.0f);
            accG[mi][nj] = (v4f)(0.0f); accHG[mi][nj] = (v4f)(0.0f);
        }

    int lrow = lane >> 3, lcol = (lane & 7) * 8;

    for (int phase = 0; phase < 2; ++phase) {
        const unsigned short* A = phase ? hbf : feat;
        int astr = phase ? D : fstride;
        const unsigned short* W = phase ? Whhb : Wihb;
        for (int k0 = 0; k0 < D; k0 += 64) {
#pragma unroll
            for (int c = 0; c < 2; ++c) {
                int row = wave * 16 + c * 8 + lrow;
                int gm = bm + row; if (gm >= Nn) gm = Nn - 1;
                __builtin_amdgcn_global_load_lds(
                    (const GLOBAL_AS unsigned int*)(A + (size_t)gm * astr + k0 + lcol),
                    (LDS_AS unsigned int*)(&As[row * 64 + lcol]), 16, 0, 0);
            }
#pragma unroll
            for (int c = 0; c < 6; ++c) {
                int row = wave * 48 + c * 8 + lrow;   // 0..191
                int g = row >> 6, dloc = row & 63;
                __builtin_amdgcn_global_load_lds(
                    (const GLOBAL_AS unsigned int*)(W + ((size_t)(g * D + bn + dloc)) * D + k0 + lcol),
                    (LDS_AS unsigned int*)(&Bs[row * 64 + lcol]), 16, 0, 0);
            }
            __syncthreads();
#pragma unroll
            for (int ks = 0; ks < 2; ++ks) {
                v8s am[2];
#pragma unroll
                for (int mi = 0; mi < 2; ++mi)
                    am[mi] = *(const v8s*)(&As[(wm * 32 + mi * 16 + ln) * 64 + ks * 32 + quad * 8]);
#pragma unroll
                for (int g = 0; g < 3; ++g) {
#pragma unroll
                    for (int nj = 0; nj < 2; ++nj) {
                        v8s bf = *(const v8s*)(&Bs[(g * 64 + wn * 32 + nj * 16 + ln) * 64 + ks * 32 + quad * 8]);
#pragma unroll
                        for (int mi = 0; mi < 2; ++mi) {
                            if (g == 0)
                                accR[mi][nj] = __builtin_amdgcn_mfma_f32_16x16x32_bf16(am[mi], bf, accR[mi][nj], 0, 0, 0);
                            else if (g == 1)
                                accZ[mi][nj] = __builtin_amdgcn_mfma_f32_16x16x32_bf16(am[mi], bf, accZ[mi][nj], 0, 0, 0);
                            else if (phase == 0)
                                accG[mi][nj] = __builtin_amdgcn_mfma_f32_16x16x32_bf16(am[mi], bf, accG[mi][nj], 0, 0, 0);
                            else
                                accHG[mi][nj] = __builtin_amdgcn_mfma_f32_16x16x32_bf16(am[mi], bf, accHG[mi][nj], 0, 0, 0);
                        }
                    }
                }
            }
            __syncthreads();
        }
    }
#pragma unroll
    for (int mi = 0; mi < 2; ++mi) {
        int gm0 = bm + wm * 32 + mi * 16 + quad * 4;
#pragma unroll
        for (int nj = 0; nj < 2; ++nj) {
            int gn = bn + wn * 32 + nj * 16 + ln;
            float vbr = gbias[gn], vbz = gbias[D + gn];
            float vbig = gbias[2 * D + gn], vbhg = gbias[3 * D + gn];
#pragma unroll
            for (int r = 0; r < 4; ++r) {
                int gm = gm0 + r;
                if (gm < Nn) {
                    float rv = 1.0f / (1.0f + expf(-(accR[mi][nj][r] + vbr)));
                    float zv = 1.0f / (1.0f + expf(-(accZ[mi][nj][r] + vbz)));
                    float nv = tanhf(accG[mi][nj][r] + vbig + rv * (accHG[mi][nj][r] + vbhg));
                    float hold = h[(size_t)gm * D + gn];
                    float hv = (1.0f - zv) * nv + zv * hold;
                    if (write_f32) h[(size_t)gm * D + gn] = hv;
                    hb[(size_t)gm * D + gn] = f2bu(hv);
                }
            }
        }
    }
}

// ------- GCN aggregate helpers ----------
__device__ __forceinline__ void agg_edge1(const ushort4* __restrict__ tbl, int lane,
                                          int2 e, float (&a)[4][4]) {
    float w = __int_as_float(e.y);
    ushort4 u[4];
#pragma unroll
    for (int q = 0; q < 4; ++q) u[q] = tbl[(size_t)e.x * D + lane + q * 64];
#pragma unroll
    for (int q = 0; q < 4; ++q) {
        a[q][0] = fmaf(w, b2f(u[q].x), a[q][0]);
        a[q][1] = fmaf(w, b2f(u[q].y), a[q][1]);
        a[q][2] = fmaf(w, b2f(u[q].z), a[q][2]);
        a[q][3] = fmaf(w, b2f(u[q].w), a[q][3]);
    }
}
__device__ __forceinline__ void agg_edge2(const ushort4* __restrict__ tbl, int lane,
                                          int2 eA, int2 eB, float (&a)[4][4]) {
    float wA = __int_as_float(eA.y), wB = __int_as_float(eB.y);
    ushort4 uA[4], uB[4];
#pragma unroll
    for (int q = 0; q < 4; ++q) {
        uA[q] = tbl[(size_t)eA.x * D + lane + q * 64];
        uB[q] = tbl[(size_t)eB.x * D + lane + q * 64];
    }
#pragma unroll
    for (int q = 0; q < 4; ++q) {
        a[q][0] = fmaf(wA, b2f(uA[q].x), a[q][0]);
        a[q][1] = fmaf(wA, b2f(uA[q].y), a[q][1]);
        a[q][2] = fmaf(wA, b2f(uA[q].z), a[q][2]);
        a[q][3] = fmaf(wA, b2f(uA[q].w), a[q][3]);
        a[q][0] = fmaf(wB, b2f(uB[q].x), a[q][0]);
        a[q][1] = fmaf(wB, b2f(uB[q].y), a[q][1]);
        a[q][2] = fmaf(wB, b2f(uB[q].z), a[q][2]);
        a[q][3] = fmaf(wB, b2f(uB[q].w), a[q][3]);
    }
}

// ------- GCN aggregate (4 snaps) + bias + LN + ReLU; one WAVE per TWO nodes ------
// 16 concurrent 8B gathers per wave (2 nodes x 2-edge unroll x 4 dim-segs).
// All loop control is wave-uniform (scalar branches, no divergence).
__global__ __launch_bounds__(256) void gcn_agg_ln_relu4_kernel(
    const unsigned short* __restrict__ hWb, const int* __restrict__ rowptr,
    const int2* __restrict__ esw,
    const float* __restrict__ selfnorm,
    const float* __restrict__ gcn_b, const float* __restrict__ ln_g,
    const float* __restrict__ ln_b, unsigned short* __restrict__ out)
{
    int wave = threadIdx.x >> 6, lane = threadIdx.x & 63;
    int i0 = blockIdx.x * 8 + wave * 2, i1 = i0 + 1;
    const ushort4* tbl = (const ushort4*)hWb;

    float a0[4][4], a1[4][4];   // [q dim-seg][s snap]
    {
        float w0 = selfnorm[i0], w1 = selfnorm[i1];
#pragma unroll
        for (int q = 0; q < 4; ++q) {
            ushort4 u0 = tbl[(size_t)i0 * D + lane + q * 64];
            ushort4 u1 = tbl[(size_t)i1 * D + lane + q * 64];
            a0[q][0] = w0 * b2f(u0.x); a0[q][1] = w0 * b2f(u0.y);
            a0[q][2] = w0 * b2f(u0.z); a0[q][3] = w0 * b2f(u0.w);
            a1[q][0] = w1 * b2f(u1.x); a1[q][1] = w1 * b2f(u1.y);
            a1[q][2] = w1 * b2f(u1.z); a1[q][3] = w1 * b2f(u1.w);
        }
    }
    int p0 = rowptr[i0], e0 = rowptr[i0 + 1];
    int p1 = e0, e1 = rowptr[i1 + 1];   // CSR rows contiguous: rowptr[i1] == e0

    // joint loop: 4 edges (2 per node) per iteration -> 16 gathers in flight
    while (p0 + 2 <= e0 && p1 + 2 <= e1) {
        int2 eA0 = esw[p0], eB0 = esw[p0 + 1];
        int2 eA1 = esw[p1], eB1 = esw[p1 + 1];
        float wA0 = __int_as_float(eA0.y), wB0 = __int_as_float(eB0.y);
        float wA1 = __int_as_float(eA1.y), wB1 = __int_as_float(eB1.y);
        ushort4 uA0[4], uB0[4], uA1[4], uB1[4];
#pragma unroll
        for (int q = 0; q < 4; ++q) {
            uA0[q] = tbl[(size_t)eA0.x * D + lane + q * 64];
            uB0[q] = tbl[(size_t)eB0.x * D + lane + q * 64];
            uA1[q] = tbl[(size_t)eA1.x * D + lane + q * 64];
            uB1[q] = tbl[(size_t)eB1.x * D + lane + q * 64];
        }
#pragma unroll
        for (int q = 0; q < 4; ++q) {
            a0[q][0] = fmaf(wA0, b2f(uA0[q].x), a0[q][0]);
            a0[q][1] = fmaf(wA0, b2f(uA0[q].y), a0[q][1]);
            a0[q][2] = fmaf(wA0, b2f(uA0[q].z), a0[q][2]);
            a0[q][3] = fmaf(wA0, b2f(uA0[q].w), a0[q][3]);
            a0[q][0] = fmaf(wB0, b2f(uB0[q].x), a0[q][0]);
            a0[q][1] = fmaf(wB0, b2f(uB0[q].y), a0[q][1]);
            a0[q][2] = fmaf(wB0, b2f(uB0[q].z), a0[q][2]);
            a0[q][3] = fmaf(wB0, b2f(uB0[q].w), a0[q][3]);
            a1[q][0] = fmaf(wA1, b2f(uA1[q].x), a1[q][0]);
            a1[q][1] = fmaf(wA1, b2f(uA1[q].y), a1[q][1]);
            a1[q][2] = fmaf(wA1, b2f(uA1[q].z), a1[q][2]);
            a1[q][3] = fmaf(wA1, b2f(uA1[q].w), a1[q][3]);
            a1[q][0] = fmaf(wB1, b2f(uB1[q].x), a1[q][0]);
            a1[q][1] = fmaf(wB1, b2f(uB1[q].y), a1[q][1]);
            a1[q][2] = fmaf(wB1, b2f(uB1[q].z), a1[q][2]);
            a1[q][3] = fmaf(wB1, b2f(uB1[q].w), a1[q][3]);
        }
        p0 += 2; p1 += 2;
    }
    // drains (wave-uniform branches)
    while (p0 + 2 <= e0) { agg_edge2(tbl, lane, esw[p0], esw[p0 + 1], a0); p0 += 2; }
    if (p0 < e0)         { agg_edge1(tbl, lane, esw[p0], a0); }
    while (p1 + 2 <= e1) { agg_edge2(tbl, lane, esw[p1], esw[p1 + 1], a1); p1 += 2; }
    if (p1 < e1)         { agg_edge1(tbl, lane, esw[p1], a1); }

#pragma unroll
    for (int q = 0; q < 4; ++q) {
        float bb = gcn_b[lane + q * 64];
        a0[q][0] += bb; a0[q][1] += bb; a0[q][2] += bb; a0[q][3] += bb;
        a1[q][0] += bb; a1[q][1] += bb; a1[q][2] += bb; a1[q][3] += bb;
    }
    float s1a[4], s2a[4], s1b[4], s2b[4];
#pragma unroll
    for (int s = 0; s < 4; ++s) {
        s1a[s] = a0[0][s] + a0[1][s] + a0[2][s] + a0[3][s];
        s2a[s] = a0[0][s] * a0[0][s] + a0[1][s] * a0[1][s]
               + a0[2][s] * a0[2][s] + a0[3][s] * a0[3][s];
        s1b[s] = a1[0][s] + a1[1][s] + a1[2][s] + a1[3][s];
        s2b[s] = a1[0][s] * a1[0][s] + a1[1][s] * a1[1][s]
               + a1[2][s] * a1[2][s] + a1[3][s] * a1[3][s];
    }
#pragma unroll
    for (int off = 32; off > 0; off >>= 1) {
#pragma unroll
        for (int s = 0; s < 4; ++s) {
            s1a[s] += __shfl_xor(s1a[s], off);
            s2a[s] += __shfl_xor(s2a[s], off);
            s1b[s] += __shfl_xor(s1b[s], off);
            s2b[s] += __shfl_xor(s2b[s], off);
        }
    }
    const float inv = 1.0f / D;
    float m0[4], r0[4], m1[4], r1[4];
#pragma unroll
    for (int s = 0; s < 4; ++s) {
        m0[s] = s1a[s] * inv;
        r0[s] = rsqrtf(s2a[s] * inv - m0[s] * m0[s] + 1e-5f);
        m1[s] = s1b[s] * inv;
        r1[s] = rsqrtf(s2b[s] * inv - m1[s] * m1[s] + 1e-5f);
    }
    size_t ob0 = (size_t)(i0 << 2) * D;
    size_t ob1 = (size_t)(i1 << 2) * D;
#pragma unroll
    for (int q = 0; q < 4; ++q) {
        int d = lane + q * 64;
        float g = ln_g[d], lb = ln_b[d];
#pragma unroll
        for (int s = 0; s < 4; ++s) {
            float y0 = (a0[q][s] - m0[s]) * r0[s] * g + lb;
            out[ob0 + (size_t)s * D + d] = f2bu(fmaxf(y0, 0.0f));
            float y1 = (a1[q][s] - m1[s]) * r1[s] * g + lb;
            out[ob1 + (size_t)s * D + d] = f2bu(fmaxf(y1, 0.0f));
        }
    }
}

// ---------------- small output head: C[M,5] = A_bf16[M,K] * W[5,K]^T + b ----------
__global__ void head5_bf_kernel(const unsigned short* __restrict__ A,
                                const float* __restrict__ W,
                                const float* __restrict__ b, float* __restrict__ C,
                                int M, int K) {
    int idx = blockIdx.x * blockDim.x + threadIdx.x;
    if (idx >= M * H) return;
    int m = idx / H;
    int h = idx - m * H;
    const ushort4* ar = (const ushort4*)(A + (size_t)m * K);
    const float* wr = W + (size_t)h * K;
    float s = 0.0f;
    for (int k4 = 0; k4 < K / 4; ++k4) {
        ushort4 u = ar[k4];
        s = fmaf(b2f(u.x), wr[4 * k4 + 0], s);
        s = fmaf(b2f(u.y), wr[4 * k4 + 1], s);
        s = fmaf(b2f(u.z), wr[4 * k4 + 2], s);
        s = fmaf(b2f(u.w), wr[4 * k4 + 3], s);
    }
    C[idx] = s + b[h];
}

extern "C" void kernel_launch(void* const* d_in, const int* in_sizes, int n_in,
                              void* d_out, int out_size, void* d_ws, size_t ws_size,
                              hipStream_t stream)
{
    const float* x     = (const float*)d_in[0];
    const int*   esrc  = (const int*)d_in[1];
    const int*   edst  = (const int*)d_in[2];
    const float* ew    = (const float*)d_in[3];
    const float* gcn_W = (const float*)d_in[4];
    const float* gcn_b = (const float*)d_in[5];
    const float* ln_g  = (const float*)d_in[6];
    const float* ln_b  = (const float*)d_in[7];
    const float* Wih   = (const float*)d_in[8];
    const float* Whh   = (const float*)d_in[9];
    const float* bih   = (const float*)d_in[10];
    const float* bhh   = (const float*)d_in[11];
    const float* fc1W  = (const float*)d_in[12];
    const float* fc1b  = (const float*)d_in[13];
    const float* fc2W  = (const float*)d_in[14];
    const float* fc2b  = (const float*)d_in[15];
    const float* fc3W  = (const float*)d_in[16];
    const float* fc3b  = (const float*)d_in[17];
    const float* dh1W  = (const float*)d_in[18];
    const float* dh1b  = (const float*)d_in[19];
    const float* dh2W  = (const float*)d_in[20];
    const float* dh2b  = (const float*)d_in[21];

    float* out = (float*)d_out;   // [Nn*H forecast][Nn*H direction]

    // workspace carve-out (aligned to 256B); total ~128 MB
    char* p = (char*)d_ws;
    auto alloc = [&](size_t bytes) -> void* {
        void* r = (void*)p;
        p += (bytes + 255) & ~(size_t)255;
        return r;
    };
    float* deg      = (float*)alloc((size_t)Nn * 4);
    float* dinv     = (float*)alloc((size_t)Nn * 4);
    float* selfnorm = (float*)alloc((size_t)Nn * 4);
    int*   rowptr   = (int*)alloc((size_t)(Nn + 1) * 4);
    int*   cnt      = (int*)alloc((size_t)Nn * 4);
    int2*  esw      = (int2*)alloc((size_t)E * 8);
    unsigned short* Wtb   = (unsigned short*)alloc((size_t)L * D * D * 2);
    unsigned short* Wihb  = (unsigned short*)alloc((size_t)3 * D * D * 2);
    unsigned short* Whhb  = (unsigned short*)alloc((size_t)3 * D * D * 2);
    unsigned short* fc1Wb = (unsigned short*)alloc((size_t)128 * 256 * 2);
    unsigned short* fc2Wb = (unsigned short*)alloc((size_t)64 * 128 * 2);
    unsigned short* dh1Wb = (unsigned short*)alloc((size_t)64 * 256 * 2);
    float* gbias    = (float*)alloc((size_t)4 * D * 4);
    unsigned short* bufA  = (unsigned short*)alloc((size_t)Nn * S * D * 2);    // 41MB
    unsigned short* hWb   = (unsigned short*)alloc((size_t)Nn * D * S * 2);    // 41MB
    float* hgru     = (float*)alloc((size_t)Nn * D * 4);                       // 20.5MB
    unsigned short* hgru_bf = (unsigned short*)alloc((size_t)Nn * D * 2);      // 10.2MB
    unsigned short* f1 = (unsigned short*)alloc((size_t)Nn * 128 * 2);         // 5.1MB
    unsigned short* f2 = (unsigned short*)alloc((size_t)Nn * 64 * 2);          // 2.6MB
    unsigned short* d1 = (unsigned short*)alloc((size_t)Nn * 64 * 2);          // 2.6MB

    auto cdiv = [](int a, int b) { return (a + b - 1) / b; };

    // ---- graph + weight preprocessing ----
    init_deg_cnt_kernel<<<cdiv(Nn, 256), 256, 0, stream>>>(deg, cnt, Nn);
    deg_hist_kernel<<<cdiv(E, 256), 256, 0, stream>>>(edst, ew, deg, cnt, E);
    dinv_kernel<<<cdiv(Nn, 256), 256, 0, stream>>>(deg, dinv, selfnorm, Nn);
    scan_rowptr_kernel<<<1, 1024, 0, stream>>>(cnt, rowptr, Nn);
    csr_fill_kernel<<<cdiv(E, 256), 256, 0, stream>>>(esrc, edst, ew, dinv, rowptr, cnt, esw, E);
    convert_weights_kernel<<<cdiv(CW6, 256), 256, 0, stream>>>(
        gcn_W, Wih, Whh, fc1W, fc2W, dh1W, bih, bhh,
        Wtb, Wihb, Whhb, fc1Wb, fc2Wb, dh1Wb, gbias);
    init_h_kernel<<<cdiv(Nn * D, 256), 256, 0, stream>>>(hgru, hgru_bf, Nn * D);
    x_to_blocked_kernel<<<cdiv(Nn * S * D / 4, 256), 256, 0, stream>>>(x, bufA);

    // ---- batched GCN stack: all 4 snapshots at once ----
    for (int l = 0; l < L; ++l) {
        dim3 g1(D / GBN, (Nn * S) / GBM);   // (2, 625)
        gemm_bt_bf16_kernel<2, 0><<<g1, 256, 0, stream>>>(
            bufA, D, Wtb + (size_t)l * D * D, nullptr, hWb, Nn * S, D, D);
        gcn_agg_ln_relu4_kernel<<<Nn / 8, 256, 0, stream>>>(
            hWb, rowptr, esw, selfnorm,
            gcn_b + (size_t)l * D, ln_g + (size_t)l * D, ln_b + (size_t)l * D, bufA);
    }

    // ---- fused GRU loop (1 kernel per snapshot) ----
    for (int s = 0; s < S; ++s) {
        dim3 g2(D / 64, cdiv(Nn, 64));   // (4, 313)
        gru_fused_kernel<<<g2, 256, 0, stream>>>(
            bufA + (size_t)s * D, S * D, hgru_bf, Wihb, Whhb, gbias,
            hgru, hgru_bf, (s < S - 1) ? 1 : 0);
    }

    // ---- heads (bf16 MFMA, fused gelu) ----
    {
        dim3 gf1(1, cdiv(Nn, GBM));
        gemm_bt_bf16_kernel<1, 1><<<gf1, 256, 0, stream>>>(
            hgru_bf, D, fc1Wb, fc1b, f1, Nn, 128, 256);
        gemm_bt_bf16_kernel<1, 1><<<gf1, 256, 0, stream>>>(
            f1, 128, fc2Wb, fc2b, f2, Nn, 64, 128);
        head5_bf_kernel<<<cdiv(Nn * H, 256), 256, 0, stream>>>(f2, fc3W, fc3b, out, Nn, 64);
        gemm_bt_bf16_kernel<1, 1><<<gf1, 256, 0, stream>>>(
            hgru_bf, D, dh1Wb, dh1b, d1, Nn, 64, 256);
        head5_bf_kernel<<<cdiv(Nn * H, 256), 256, 0, stream>>>(d1, dh2W, dh2b, out + (size_t)Nn * H, Nn, 64);
    }
}